// Round 9
// baseline (77.036 us; speedup 1.0000x reference)
//
#include <hip/hip_runtime.h>

// PIQuantumDQN: 4-qubit, 5-layer re-uploading circuit, B=524288 samples.
// R9: state evolution in PACKED F16 (v_pk_*_f16 is full-rate = 2x f32 on
// CDNA4; pk-f32 measured 2-pass in R7). All gates as range-safe 3-shear
// planar rotations (x-=t*y; y+=s*x; x-=t*y with t=tan(phi/2), s=sin(phi);
// |t|<=1 after reducing phi into (-pi/2,pi/2] -- the dropped -I per reduced
// RX gate is a global phase, invisible in probs). Angles/trig/epilogue f32.
// Two samples per thread packed per f16x2 VGPR.
// wire q (0 = MSB) <-> bit (3-q) of the flat index, so mask(q) = 8 >> q.

typedef _Float16 h2 __attribute__((ext_vector_type(2)));
typedef float v2f __attribute__((ext_vector_type(2)));

__device__ __forceinline__ float rfl(float v) {
    return __uint_as_float(__builtin_amdgcn_readfirstlane(__float_as_uint(v)));
}

// wave-uniform f32 -> packed duplicated f16x2 held in an SGPR
__device__ __forceinline__ h2 usplat_h2(float v) {
    _Float16 h = (_Float16)v;
    unsigned short us = __builtin_bit_cast(unsigned short, h);
    unsigned u = (unsigned)us | ((unsigned)us << 16);
    u = __builtin_amdgcn_readfirstlane(u);
    return __builtin_bit_cast(h2, u);
}

// RY gate: rotate (re0,re1) and (im0,im1) by angle a: [c -s; s c]
template<int MASK>
__device__ __forceinline__ void apply_ry_sh(h2 (&re)[16], h2 (&im)[16], h2 t, h2 s) {
#pragma unroll
    for (int i0 = 0; i0 < 16; ++i0) {
        if (i0 & MASK) continue;
        const int i1 = i0 | MASK;
        h2 x, y;
        x = re[i0]; y = re[i1];
        x = x - t * y; y = y + s * x; x = x - t * y;
        re[i0] = x; re[i1] = y;
        x = im[i0]; y = im[i1];
        x = x - t * y; y = y + s * x; x = x - t * y;
        im[i0] = x; im[i1] = y;
    }
}

// RX gate: plane (r0,m1) rotated by -phi ([c s; -s c]), plane (m0,r1) by +phi
template<int MASK>
__device__ __forceinline__ void apply_rx_sh(h2 (&re)[16], h2 (&im)[16], h2 t, h2 s) {
#pragma unroll
    for (int i0 = 0; i0 < 16; ++i0) {
        if (i0 & MASK) continue;
        const int i1 = i0 | MASK;
        h2 x, y;
        x = re[i0]; y = im[i1];                   // R(-phi)
        x = x + t * y; y = y - s * x; x = x + t * y;
        re[i0] = x; im[i1] = y;
        x = im[i0]; y = re[i1];                   // R(+phi)
        x = x - t * y; y = y + s * x; x = x - t * y;
        im[i0] = x; re[i1] = y;
    }
}

template<int CMASK, int TMASK>
__device__ __forceinline__ void apply_cnot(h2 (&re)[16], h2 (&im)[16]) {
#pragma unroll
    for (int i = 0; i < 16; ++i) {
        if ((i & CMASK) && !(i & TMASK)) {
            const int j = i | TMASK;
            h2 tr = re[i]; re[i] = re[j]; re[j] = tr;
            h2 ti = im[i]; im[i] = im[j]; im[j] = ti;
        }
    }
}

__global__ __launch_bounds__(256) void qdqn_kernel(
    const float* __restrict__ x,        // (B,4) fp32
    const float* __restrict__ weights,  // (5,4) fp32
    const float* __restrict__ Wm,       // (2,4) fp32
    const float* __restrict__ bv,       // (2,)  fp32
    float4* __restrict__ out,           // (B/2,4): two float2 outputs packed
    int Bh)                             // B/2 threads
{
    // ---- uniforms (SGPR) ----
    // layer-0 gates (k=0..3): unreduced cos/sin(w/2) as f32 for the product state.
    // layers 1-4 gates (k=4..19): reduced-angle shear coeffs t=tan(phi/2), s=sin(phi),
    // phi = w/2 reduced into (-pi/2, pi/2] (global-phase -I dropped).
    const float INV_4PI = 0.07957747154594767f;   // w/2 rad -> revolutions
    float cw0[4], sw0[4];
    h2 rxt[16], rxs[16];
#pragma unroll
    for (int k = 0; k < 20; ++k) {
        float rev = weights[k] * INV_4PI;         // uniform -> scalar load
        if (k < 4) {
            cw0[k] = rfl(__builtin_amdgcn_cosf(rev));
            sw0[k] = rfl(__builtin_amdgcn_sinf(rev));
        } else {
            float r2 = (rev > 0.25f) ? (rev - 0.5f) : rev;   // phi in (-pi/2, pi/2]
            float c = __builtin_amdgcn_cosf(r2);             // >= 0
            float s = __builtin_amdgcn_sinf(r2);
            float t = s * __builtin_amdgcn_rcpf(1.0f + c);   // |t| <= 1
            rxt[k - 4] = usplat_h2(t);
            rxs[k - 4] = usplat_h2(s);
        }
    }
    float Wu[8];
#pragma unroll
    for (int k = 0; k < 8; ++k) Wu[k] = rfl(Wm[k]);
    const float b0u = rfl(bv[0]);
    const float b1u = rfl(bv[1]);

    const int tid = blockIdx.x * blockDim.x + threadIdx.x;
    if (tid >= Bh) return;

    // ---- two consecutive samples ----
    const float4 xA = ((const float4*)x)[2 * tid];
    const float4 xB = ((const float4*)x)[2 * tid + 1];
    float xvA[4] = { xA.x, xA.y, xA.z, xA.w };
    float xvB[4] = { xB.x, xB.y, xB.z, xB.w };

    // per-qubit per-sample RY trig (f32): a = xn*pi/2, rev = xn*0.25, |rev|<=0.25
    const float inv_bounds4[4] = { 0.25f / 4.8f, 0.25f / 4.0f, 0.25f / 0.418f, 0.25f / 4.0f };
    float caA[4], saA[4], caB[4], saB[4];
    h2 ryt[4], rys[4];
#pragma unroll
    for (int q = 0; q < 4; ++q) {
        float ra = fminf(fmaxf(xvA[q] * inv_bounds4[q], -0.25f), 0.25f);
        float rb = fminf(fmaxf(xvB[q] * inv_bounds4[q], -0.25f), 0.25f);
        saA[q] = __builtin_amdgcn_sinf(ra);  caA[q] = __builtin_amdgcn_cosf(ra);
        saB[q] = __builtin_amdgcn_sinf(rb);  caB[q] = __builtin_amdgcn_cosf(rb);
        float tA = saA[q] * __builtin_amdgcn_rcpf(1.0f + caA[q]);   // |t|<=1 (c>=0)
        float tB = saB[q] * __builtin_amdgcn_rcpf(1.0f + caB[q]);
        ryt[q] = (h2){ (_Float16)tA, (_Float16)tB };
        rys[q] = (h2){ (_Float16)saA[q], (_Float16)saB[q] };
    }

    // ---- layer 0: product state RX(w)RY(a)|0> = (alpha, beta), unitary ----
    //   alpha = (cw*ca, -sw*sa), beta = (cw*sa, -sw*ca)
    h2 ar[4], ai[4], br[4], bi[4];
#pragma unroll
    for (int q = 0; q < 4; ++q) {
        ar[q] = (h2){ (_Float16)( cw0[q] * caA[q]), (_Float16)( cw0[q] * caB[q]) };
        ai[q] = (h2){ (_Float16)(-sw0[q] * saA[q]), (_Float16)(-sw0[q] * saB[q]) };
        br[q] = (h2){ (_Float16)( cw0[q] * saA[q]), (_Float16)( cw0[q] * saB[q]) };
        bi[q] = (h2){ (_Float16)(-sw0[q] * caA[q]), (_Float16)(-sw0[q] * caB[q]) };
    }
    // tensor product (f16 pk), wire 0 = MSB
    h2 t2r[4], t2i[4];
#pragma unroll
    for (int i = 0; i < 4; ++i) {
        h2 xr = (i & 2) ? br[0] : ar[0], xi = (i & 2) ? bi[0] : ai[0];
        h2 yr = (i & 1) ? br[1] : ar[1], yi = (i & 1) ? bi[1] : ai[1];
        t2r[i] = xr * yr - xi * yi;
        t2i[i] = xr * yi + xi * yr;
    }
    h2 t3r[8], t3i[8];
#pragma unroll
    for (int i = 0; i < 8; ++i) {
        h2 xr = t2r[i >> 1], xi = t2i[i >> 1];
        h2 yr = (i & 1) ? br[2] : ar[2], yi = (i & 1) ? bi[2] : ai[2];
        t3r[i] = xr * yr - xi * yi;
        t3i[i] = xr * yi + xi * yr;
    }
    h2 re[16], im[16];
#pragma unroll
    for (int i = 0; i < 16; ++i) {
        h2 xr = t3r[i >> 1], xi = t3i[i >> 1];
        h2 yr = (i & 1) ? br[3] : ar[3], yi = (i & 1) ? bi[3] : ai[3];
        re[i] = xr * yr - xi * yi;
        im[i] = xr * yi + xi * yr;
    }
    apply_cnot<8, 4>(re, im);
    apply_cnot<4, 2>(re, im);
    apply_cnot<2, 1>(re, im);
    apply_cnot<1, 8>(re, im);

    // ---- layers 1..4: shear-form RY then RX, then CNOT ring ----
#pragma unroll
    for (int l = 1; l < 5; ++l) {
        apply_ry_sh<8>(re, im, ryt[0], rys[0]);
        apply_ry_sh<4>(re, im, ryt[1], rys[1]);
        apply_ry_sh<2>(re, im, ryt[2], rys[2]);
        apply_ry_sh<1>(re, im, ryt[3], rys[3]);
        const int k = (l - 1) * 4;
        apply_rx_sh<8>(re, im, rxt[k + 0], rxs[k + 0]);
        apply_rx_sh<4>(re, im, rxt[k + 1], rxs[k + 1]);
        apply_rx_sh<2>(re, im, rxt[k + 2], rxs[k + 2]);
        apply_rx_sh<1>(re, im, rxt[k + 3], rxs[k + 3]);
        apply_cnot<8, 4>(re, im);
        apply_cnot<4, 2>(re, im);
        apply_cnot<2, 1>(re, im);
        apply_cnot<1, 8>(re, im);
    }

    // ---- probs (f16 squares) -> f32 sign tree -> linear layer ----
    v2f p[16];
#pragma unroll
    for (int i = 0; i < 16; ++i) {
        h2 ph = re[i] * re[i] + im[i] * im[i];
        p[i] = (v2f){ (float)ph.x, (float)ph.y };
    }
    v2f tt[8];
#pragma unroll
    for (int i = 0; i < 8; ++i) tt[i] = p[2 * i] + p[2 * i + 1];
    v2f u[4];
#pragma unroll
    for (int i = 0; i < 4; ++i) u[i] = tt[2 * i] + tt[2 * i + 1];
    const v2f z0 = (u[0] + u[1]) - (u[2] + u[3]);               // wire 0 (bit 3)
    const v2f z1 = (u[0] - u[1]) + (u[2] - u[3]);               // wire 1 (bit 2)
    const v2f z2 = (tt[0] - tt[1]) + (tt[2] - tt[3])
                 + (tt[4] - tt[5]) + (tt[6] - tt[7]);           // wire 2 (bit 1)
    const v2f z3 = ((p[0] - p[1]) + (p[2] - p[3]))
                 + ((p[4] - p[5]) + (p[6] - p[7]))
                 + ((p[8] - p[9]) + (p[10] - p[11]))
                 + ((p[12] - p[13]) + (p[14] - p[15]));         // wire 3 (bit 0)

    v2f o0 = (v2f){b0u, b0u}, o1 = (v2f){b1u, b1u};
    o0 = (v2f){Wu[0], Wu[0]} * z0 + o0; o0 = (v2f){Wu[1], Wu[1]} * z1 + o0;
    o0 = (v2f){Wu[2], Wu[2]} * z2 + o0; o0 = (v2f){Wu[3], Wu[3]} * z3 + o0;
    o1 = (v2f){Wu[4], Wu[4]} * z0 + o1; o1 = (v2f){Wu[5], Wu[5]} * z1 + o1;
    o1 = (v2f){Wu[6], Wu[6]} * z2 + o1; o1 = (v2f){Wu[7], Wu[7]} * z3 + o1;

    out[tid] = make_float4(o0.x, o1.x, o0.y, o1.y);   // 16B coalesced store
}

extern "C" void kernel_launch(void* const* d_in, const int* in_sizes, int n_in,
                              void* d_out, int out_size, void* d_ws, size_t ws_size,
                              hipStream_t stream) {
    const float* x  = (const float*)d_in[0];
    const float* w  = (const float*)d_in[1];
    const float* Wm = (const float*)d_in[2];
    const float* bv = (const float*)d_in[3];
    float4* out = (float4*)d_out;

    const int B  = in_sizes[0] / 4;
    const int Bh = B / 2;                       // B is even (524288)
    dim3 grid((Bh + 255) / 256), block(256);
    qdqn_kernel<<<grid, block, 0, stream>>>(x, w, Wm, bv, out, Bh);
}

// Round 10
// 75.377 us; speedup vs baseline: 1.0220x; 1.0220x over previous
//
#include <hip/hip_runtime.h>

// PIQuantumDQN: 4-qubit, 5-layer re-uploading circuit, B=524288 samples.
// R10: f32 packed (2 samples/thread, v_pk_* — R7/R9 showed the limiter is
// packed-instruction count; pk-f16 == pk-f32 per inst). Minimal gate forms:
//   RY = 3-shear (6 FMA/pair, exactly unitary; t=tan(phi/2)=s/(1+c), |t|<=1)
//   RX = tangent (4 FMA/pair; uniform cos(w/2) factors fold into Wu via S^2)
// => 320 pk-insts/layer vs R8/R9's 384. Layer 0 stays product-state.
// wire q (0 = MSB) <-> bit (3-q) of the flat index, so mask(q) = 8 >> q.

typedef float v2f __attribute__((ext_vector_type(2)));

__device__ __forceinline__ v2f splat(float x) { return (v2f){x, x}; }

__device__ __forceinline__ float rfl(float v) {
    return __uint_as_float(__builtin_amdgcn_readfirstlane(__float_as_uint(v)));
}

// RY via 3 shears: plane rotation by phi with c=cos(phi), s=sin(phi),
// t=tan(phi/2):  x -= t*y; y += s*x; x -= t*y  ==> (c*x - s*y, s*x + c*y)
template<int MASK>
__device__ __forceinline__ void apply_ry_sh(v2f (&re)[16], v2f (&im)[16], v2f t, v2f s) {
#pragma unroll
    for (int i0 = 0; i0 < 16; ++i0) {
        if (i0 & MASK) continue;
        const int i1 = i0 | MASK;
        v2f x, y;
        x = re[i0]; y = re[i1];
        x = x - t * y; y = y + s * x; x = x - t * y;
        re[i0] = x; re[i1] = y;
        x = im[i0]; y = im[i1];
        x = x - t * y; y = y + s * x; x = x - t * y;
        im[i0] = x; im[i1] = y;
    }
}

// RX tangent form (t = tan(w/2)); true output = cos(w/2) * (this output).
template<int MASK>
__device__ __forceinline__ void apply_rx_t(v2f (&re)[16], v2f (&im)[16], v2f t) {
#pragma unroll
    for (int i0 = 0; i0 < 16; ++i0) {
        if (i0 & MASK) continue;
        const int i1 = i0 | MASK;
        v2f r0 = re[i0], r1 = re[i1];
        v2f m0 = im[i0], m1 = im[i1];
        re[i0] = t * m1 + r0;
        im[i0] = m0 - t * r1;
        re[i1] = t * m0 + r1;
        im[i1] = m1 - t * r0;
    }
}

template<int CMASK, int TMASK>
__device__ __forceinline__ void apply_cnot(v2f (&re)[16], v2f (&im)[16]) {
#pragma unroll
    for (int i = 0; i < 16; ++i) {
        if ((i & CMASK) && !(i & TMASK)) {
            const int j = i | TMASK;
            v2f tr = re[i]; re[i] = re[j]; re[j] = tr;
            v2f ti = im[i]; im[i] = im[j]; im[j] = ti;
        }
    }
}

__global__ __launch_bounds__(256) void qdqn_kernel(
    const float* __restrict__ x,        // (B,4) fp32
    const float* __restrict__ weights,  // (5,4) fp32
    const float* __restrict__ Wm,       // (2,4) fp32
    const float* __restrict__ bv,       // (2,)  fp32
    float4* __restrict__ out,           // (B/2,4): two float2 outputs packed
    int Bh)                             // B/2 threads
{
    // ---- uniforms: tan(w/2) per gate + accumulated scale S = prod cos(w/2) ----
    float tw[20];
    float S = 1.0f;
    const float INV_4PI = 0.07957747154594767f;   // w/2 rad = w*(1/4pi) rev
#pragma unroll
    for (int k = 0; k < 20; ++k) {
        float rev = weights[k] * INV_4PI;         // uniform -> scalar load
        float c = __builtin_amdgcn_cosf(rev);
        float s = __builtin_amdgcn_sinf(rev);
        tw[k] = rfl(s * __builtin_amdgcn_rcpf(c));
        S *= c;
    }
    S = rfl(S);
    const float S2 = S * S;                       // probs scale by S^2
    float Wu[8];
#pragma unroll
    for (int k = 0; k < 8; ++k) Wu[k] = rfl(Wm[k] * S2);   // fold scale here
    const float b0u = rfl(bv[0]);
    const float b1u = rfl(bv[1]);

    const int t = blockIdx.x * blockDim.x + threadIdx.x;
    if (t >= Bh) return;

    // ---- load two consecutive samples, pack component-wise into v2f ----
    const float4 xA = ((const float4*)x)[2 * t];
    const float4 xB = ((const float4*)x)[2 * t + 1];
    v2f xv[4] = { (v2f){xA.x, xB.x}, (v2f){xA.y, xB.y},
                  (v2f){xA.z, xB.z}, (v2f){xA.w, xB.w} };

    // RY rotation angle phi = xn*pi/2: rev = xn*0.25, |rev|<=0.25 (no reduction).
    // rc = cos(phi) >= 0, rs = sin(phi), ryt = tan(phi/2) = rs/(1+rc), |ryt|<=1.
    const float inv_bounds4[4] = { 0.25f / 4.8f, 0.25f / 4.0f, 0.25f / 0.418f, 0.25f / 4.0f };
    v2f rc[4], rs[4], ryt[4];
#pragma unroll
    for (int q = 0; q < 4; ++q) {
        v2f rev = xv[q] * splat(inv_bounds4[q]);
        float ra = fminf(fmaxf(rev.x, -0.25f), 0.25f);
        float rb = fminf(fmaxf(rev.y, -0.25f), 0.25f);
        float sa = __builtin_amdgcn_sinf(ra), ca = __builtin_amdgcn_cosf(ra);
        float sb = __builtin_amdgcn_sinf(rb), cb = __builtin_amdgcn_cosf(rb);
        rs[q] = (v2f){ sa, sb };
        rc[q] = (v2f){ ca, cb };
        ryt[q] = (v2f){ sa * __builtin_amdgcn_rcpf(1.0f + ca),
                        sb * __builtin_amdgcn_rcpf(1.0f + cb) };
    }

    // ---- layer 0 (separable until first CNOT), RX part in tangent form ----
    // (1/cw)*RX(w)RY(a)|0> = (alpha, beta): alpha = (ca, -t*sa), beta = (sa, -t*ca)
    v2f ar[4], ai[4], br[4], bi[4];
#pragma unroll
    for (int q = 0; q < 4; ++q) {
        v2f tq = splat(tw[q]);
        ar[q] = rc[q];
        ai[q] = -(tq * rs[q]);
        br[q] = rs[q];
        bi[q] = -(tq * rc[q]);
    }
    // tensor product, wire 0 = MSB
    v2f t2r[4], t2i[4];
#pragma unroll
    for (int i = 0; i < 4; ++i) {
        v2f xr = (i & 2) ? br[0] : ar[0], xi = (i & 2) ? bi[0] : ai[0];
        v2f yr = (i & 1) ? br[1] : ar[1], yi = (i & 1) ? bi[1] : ai[1];
        t2r[i] = xr * yr - xi * yi;
        t2i[i] = xr * yi + xi * yr;
    }
    v2f t3r[8], t3i[8];
#pragma unroll
    for (int i = 0; i < 8; ++i) {
        v2f xr = t2r[i >> 1], xi = t2i[i >> 1];
        v2f yr = (i & 1) ? br[2] : ar[2], yi = (i & 1) ? bi[2] : ai[2];
        t3r[i] = xr * yr - xi * yi;
        t3i[i] = xr * yi + xi * yr;
    }
    v2f re[16], im[16];
#pragma unroll
    for (int i = 0; i < 16; ++i) {
        v2f xr = t3r[i >> 1], xi = t3i[i >> 1];
        v2f yr = (i & 1) ? br[3] : ar[3], yi = (i & 1) ? bi[3] : ai[3];
        re[i] = xr * yr - xi * yi;
        im[i] = xr * yi + xi * yr;
    }
    apply_cnot<8, 4>(re, im);
    apply_cnot<4, 2>(re, im);
    apply_cnot<2, 1>(re, im);
    apply_cnot<1, 8>(re, im);

    // ---- layers 1..4: shear RY (6/pair), tangent RX (4/pair), free CNOTs ----
#pragma unroll
    for (int l = 1; l < 5; ++l) {
        apply_ry_sh<8>(re, im, ryt[0], rs[0]);
        apply_ry_sh<4>(re, im, ryt[1], rs[1]);
        apply_ry_sh<2>(re, im, ryt[2], rs[2]);
        apply_ry_sh<1>(re, im, ryt[3], rs[3]);
        apply_rx_t<8>(re, im, splat(tw[l * 4 + 0]));
        apply_rx_t<4>(re, im, splat(tw[l * 4 + 1]));
        apply_rx_t<2>(re, im, splat(tw[l * 4 + 2]));
        apply_rx_t<1>(re, im, splat(tw[l * 4 + 3]));
        apply_cnot<8, 4>(re, im);
        apply_cnot<4, 2>(re, im);
        apply_cnot<2, 1>(re, im);
        apply_cnot<1, 8>(re, im);
    }

    // ---- probs -> <Z_q> sign tree -> linear layer (scale folded in Wu) ----
    v2f p[16];
#pragma unroll
    for (int i = 0; i < 16; ++i) p[i] = re[i] * re[i] + im[i] * im[i];
    v2f tt[8];
#pragma unroll
    for (int i = 0; i < 8; ++i) tt[i] = p[2 * i] + p[2 * i + 1];
    v2f u[4];
#pragma unroll
    for (int i = 0; i < 4; ++i) u[i] = tt[2 * i] + tt[2 * i + 1];
    const v2f z0 = (u[0] + u[1]) - (u[2] + u[3]);               // wire 0 (bit 3)
    const v2f z1 = (u[0] - u[1]) + (u[2] - u[3]);               // wire 1 (bit 2)
    const v2f z2 = (tt[0] - tt[1]) + (tt[2] - tt[3])
                 + (tt[4] - tt[5]) + (tt[6] - tt[7]);           // wire 2 (bit 1)
    const v2f z3 = ((p[0] - p[1]) + (p[2] - p[3]))
                 + ((p[4] - p[5]) + (p[6] - p[7]))
                 + ((p[8] - p[9]) + (p[10] - p[11]))
                 + ((p[12] - p[13]) + (p[14] - p[15]));         // wire 3 (bit 0)

    v2f o0 = splat(b0u), o1 = splat(b1u);
    o0 = splat(Wu[0]) * z0 + o0; o0 = splat(Wu[1]) * z1 + o0;
    o0 = splat(Wu[2]) * z2 + o0; o0 = splat(Wu[3]) * z3 + o0;
    o1 = splat(Wu[4]) * z0 + o1; o1 = splat(Wu[5]) * z1 + o1;
    o1 = splat(Wu[6]) * z2 + o1; o1 = splat(Wu[7]) * z3 + o1;

    out[t] = make_float4(o0.x, o1.x, o0.y, o1.y);   // 16B coalesced store
}

extern "C" void kernel_launch(void* const* d_in, const int* in_sizes, int n_in,
                              void* d_out, int out_size, void* d_ws, size_t ws_size,
                              hipStream_t stream) {
    const float* x  = (const float*)d_in[0];
    const float* w  = (const float*)d_in[1];
    const float* Wm = (const float*)d_in[2];
    const float* bv = (const float*)d_in[3];
    float4* out = (float4*)d_out;

    const int B  = in_sizes[0] / 4;
    const int Bh = B / 2;                       // B is even (524288)
    dim3 grid((Bh + 255) / 256), block(256);
    qdqn_kernel<<<grid, block, 0, stream>>>(x, w, Wm, bv, out, Bh);
}

// Round 11
// 75.121 us; speedup vs baseline: 1.0255x; 1.0034x over previous
//
#include <hip/hip_runtime.h>

// PIQuantumDQN: 4-qubit, 5-layer re-uploading circuit, B=524288 samples.
// R11: FOUR samples per thread as two independent v2f-packed states
// (A=samples 0,1; B=samples 2,3), interleaved per gate sweep for 2x ILP;
// wave count halves to 2 waves/SIMD (all resident), prologue amortized 2x.
// Gate forms (R10): RY 3-shear (6/pair), RX tangent (4/pair, uniform cos
// folded into Wu via S^2). pk-f32 pipe = 4 cyc/inst (2x FLOP, 2-pass).
// __launch_bounds__(256,2) caps VGPR at 256 (state 128 + temps ~90).
// wire q (0 = MSB) <-> bit (3-q) of the flat index, so mask(q) = 8 >> q.

typedef float v2f __attribute__((ext_vector_type(2)));

__device__ __forceinline__ v2f splat(float x) { return (v2f){x, x}; }

__device__ __forceinline__ float rfl(float v) {
    return __uint_as_float(__builtin_amdgcn_readfirstlane(__float_as_uint(v)));
}

// RY via 3 shears on both states (re/im planes): x-=t*y; y+=s*x; x-=t*y
template<int MASK>
__device__ __forceinline__ void apply_ry_sh2(v2f (&re)[2][16], v2f (&im)[2][16],
                                             const v2f (&t)[2], const v2f (&s)[2]) {
#pragma unroll
    for (int i0 = 0; i0 < 16; ++i0) {
        if (i0 & MASK) continue;
        const int i1 = i0 | MASK;
#pragma unroll
        for (int k = 0; k < 2; ++k) {
            v2f x, y;
            x = re[k][i0]; y = re[k][i1];
            x = x - t[k] * y; y = y + s[k] * x; x = x - t[k] * y;
            re[k][i0] = x; re[k][i1] = y;
            x = im[k][i0]; y = im[k][i1];
            x = x - t[k] * y; y = y + s[k] * x; x = x - t[k] * y;
            im[k][i0] = x; im[k][i1] = y;
        }
    }
}

// RX tangent form on both states; true output = cos(w/2) * (this output).
template<int MASK>
__device__ __forceinline__ void apply_rx_t2(v2f (&re)[2][16], v2f (&im)[2][16], v2f t) {
#pragma unroll
    for (int i0 = 0; i0 < 16; ++i0) {
        if (i0 & MASK) continue;
        const int i1 = i0 | MASK;
#pragma unroll
        for (int k = 0; k < 2; ++k) {
            v2f r0 = re[k][i0], r1 = re[k][i1];
            v2f m0 = im[k][i0], m1 = im[k][i1];
            re[k][i0] = t * m1 + r0;
            im[k][i0] = m0 - t * r1;
            re[k][i1] = t * m0 + r1;
            im[k][i1] = m1 - t * r0;
        }
    }
}

template<int CMASK, int TMASK>
__device__ __forceinline__ void apply_cnot2(v2f (&re)[2][16], v2f (&im)[2][16]) {
#pragma unroll
    for (int i = 0; i < 16; ++i) {
        if ((i & CMASK) && !(i & TMASK)) {
            const int j = i | TMASK;
#pragma unroll
            for (int k = 0; k < 2; ++k) {
                v2f tr = re[k][i]; re[k][i] = re[k][j]; re[k][j] = tr;
                v2f ti = im[k][i]; im[k][i] = im[k][j]; im[k][j] = ti;
            }
        }
    }
}

__global__ __launch_bounds__(256, 2) void qdqn_kernel(
    const float* __restrict__ x,        // (B,4) fp32
    const float* __restrict__ weights,  // (5,4) fp32
    const float* __restrict__ Wm,       // (2,4) fp32
    const float* __restrict__ bv,       // (2,)  fp32
    float4* __restrict__ out,           // (B/2,4): two float2 outputs per entry
    int Bq)                             // B/4 threads
{
    // ---- uniforms: tan(w/2) per gate + accumulated scale S = prod cos(w/2) ----
    float tw[20];
    float S = 1.0f;
    const float INV_4PI = 0.07957747154594767f;   // w/2 rad = w*(1/4pi) rev
#pragma unroll
    for (int k = 0; k < 20; ++k) {
        float rev = weights[k] * INV_4PI;         // uniform -> scalar load
        float c = __builtin_amdgcn_cosf(rev);
        float s = __builtin_amdgcn_sinf(rev);
        tw[k] = rfl(s * __builtin_amdgcn_rcpf(c));
        S *= c;
    }
    S = rfl(S);
    const float S2 = S * S;                       // probs scale by S^2
    float Wu[8];
#pragma unroll
    for (int k = 0; k < 8; ++k) Wu[k] = rfl(Wm[k] * S2);   // fold scale here
    const float b0u = rfl(bv[0]);
    const float b1u = rfl(bv[1]);

    const int t = blockIdx.x * blockDim.x + threadIdx.x;
    if (t >= Bq) return;

    // ---- load four consecutive samples, pack pairwise into two v2f streams ----
    const float4 x0 = ((const float4*)x)[4 * t + 0];
    const float4 x1 = ((const float4*)x)[4 * t + 1];
    const float4 x2 = ((const float4*)x)[4 * t + 2];
    const float4 x3 = ((const float4*)x)[4 * t + 3];
    v2f xv[2][4] = {
        { (v2f){x0.x, x1.x}, (v2f){x0.y, x1.y}, (v2f){x0.z, x1.z}, (v2f){x0.w, x1.w} },
        { (v2f){x2.x, x3.x}, (v2f){x2.y, x3.y}, (v2f){x2.z, x3.z}, (v2f){x2.w, x3.w} }
    };

    // RY angle phi = xn*pi/2: rev = xn*0.25, |rev|<=0.25.
    // rc=cos(phi)>=0, rs=sin(phi), ryt=tan(phi/2)=rs/(1+rc), |ryt|<=1.
    const float inv_bounds4[4] = { 0.25f / 4.8f, 0.25f / 4.0f, 0.25f / 0.418f, 0.25f / 4.0f };
    v2f rc[2][4], rs[2][4], ryt[2][4];
#pragma unroll
    for (int k = 0; k < 2; ++k) {
#pragma unroll
        for (int q = 0; q < 4; ++q) {
            v2f rev = xv[k][q] * splat(inv_bounds4[q]);
            float ra = fminf(fmaxf(rev.x, -0.25f), 0.25f);
            float rb = fminf(fmaxf(rev.y, -0.25f), 0.25f);
            float sa = __builtin_amdgcn_sinf(ra), ca = __builtin_amdgcn_cosf(ra);
            float sb = __builtin_amdgcn_sinf(rb), cb = __builtin_amdgcn_cosf(rb);
            rs[k][q] = (v2f){ sa, sb };
            rc[k][q] = (v2f){ ca, cb };
            ryt[k][q] = (v2f){ sa * __builtin_amdgcn_rcpf(1.0f + ca),
                               sb * __builtin_amdgcn_rcpf(1.0f + cb) };
        }
    }

    // ---- layer 0 (separable until first CNOT), RX part in tangent form ----
    // (1/cw)*RX(w)RY(a)|0> = (alpha,beta): alpha=(ca,-t*sa), beta=(sa,-t*ca)
    v2f re[2][16], im[2][16];
#pragma unroll
    for (int k = 0; k < 2; ++k) {
        v2f ar[4], ai[4], br[4], bi[4];
#pragma unroll
        for (int q = 0; q < 4; ++q) {
            v2f tq = splat(tw[q]);
            ar[q] = rc[k][q];
            ai[q] = -(tq * rs[k][q]);
            br[q] = rs[k][q];
            bi[q] = -(tq * rc[k][q]);
        }
        v2f t2r[4], t2i[4];
#pragma unroll
        for (int i = 0; i < 4; ++i) {
            v2f xr = (i & 2) ? br[0] : ar[0], xi = (i & 2) ? bi[0] : ai[0];
            v2f yr = (i & 1) ? br[1] : ar[1], yi = (i & 1) ? bi[1] : ai[1];
            t2r[i] = xr * yr - xi * yi;
            t2i[i] = xr * yi + xi * yr;
        }
        v2f t3r[8], t3i[8];
#pragma unroll
        for (int i = 0; i < 8; ++i) {
            v2f xr = t2r[i >> 1], xi = t2i[i >> 1];
            v2f yr = (i & 1) ? br[2] : ar[2], yi = (i & 1) ? bi[2] : ai[2];
            t3r[i] = xr * yr - xi * yi;
            t3i[i] = xr * yi + xi * yr;
        }
#pragma unroll
        for (int i = 0; i < 16; ++i) {
            v2f xr = t3r[i >> 1], xi = t3i[i >> 1];
            v2f yr = (i & 1) ? br[3] : ar[3], yi = (i & 1) ? bi[3] : ai[3];
            re[k][i] = xr * yr - xi * yi;
            im[k][i] = xr * yi + xi * yr;
        }
    }
    apply_cnot2<8, 4>(re, im);
    apply_cnot2<4, 2>(re, im);
    apply_cnot2<2, 1>(re, im);
    apply_cnot2<1, 8>(re, im);

    // ---- layers 1..4: shear RY (6/pair), tangent RX (4/pair), free CNOTs ----
#pragma unroll
    for (int l = 1; l < 5; ++l) {
        apply_ry_sh2<8>(re, im, { ryt[0][0], ryt[1][0] }, { rs[0][0], rs[1][0] });
        apply_ry_sh2<4>(re, im, { ryt[0][1], ryt[1][1] }, { rs[0][1], rs[1][1] });
        apply_ry_sh2<2>(re, im, { ryt[0][2], ryt[1][2] }, { rs[0][2], rs[1][2] });
        apply_ry_sh2<1>(re, im, { ryt[0][3], ryt[1][3] }, { rs[0][3], rs[1][3] });
        apply_rx_t2<8>(re, im, splat(tw[l * 4 + 0]));
        apply_rx_t2<4>(re, im, splat(tw[l * 4 + 1]));
        apply_rx_t2<2>(re, im, splat(tw[l * 4 + 2]));
        apply_rx_t2<1>(re, im, splat(tw[l * 4 + 3]));
        apply_cnot2<8, 4>(re, im);
        apply_cnot2<4, 2>(re, im);
        apply_cnot2<2, 1>(re, im);
        apply_cnot2<1, 8>(re, im);
    }

    // ---- probs -> <Z_q> sign tree -> linear layer (scale folded in Wu) ----
#pragma unroll
    for (int k = 0; k < 2; ++k) {
        v2f p[16];
#pragma unroll
        for (int i = 0; i < 16; ++i) p[i] = re[k][i] * re[k][i] + im[k][i] * im[k][i];
        v2f tt[8];
#pragma unroll
        for (int i = 0; i < 8; ++i) tt[i] = p[2 * i] + p[2 * i + 1];
        v2f u[4];
#pragma unroll
        for (int i = 0; i < 4; ++i) u[i] = tt[2 * i] + tt[2 * i + 1];
        const v2f z0 = (u[0] + u[1]) - (u[2] + u[3]);           // wire 0 (bit 3)
        const v2f z1 = (u[0] - u[1]) + (u[2] - u[3]);           // wire 1 (bit 2)
        const v2f z2 = (tt[0] - tt[1]) + (tt[2] - tt[3])
                     + (tt[4] - tt[5]) + (tt[6] - tt[7]);       // wire 2 (bit 1)
        const v2f z3 = ((p[0] - p[1]) + (p[2] - p[3]))
                     + ((p[4] - p[5]) + (p[6] - p[7]))
                     + ((p[8] - p[9]) + (p[10] - p[11]))
                     + ((p[12] - p[13]) + (p[14] - p[15]));     // wire 3 (bit 0)

        v2f o0 = splat(b0u), o1 = splat(b1u);
        o0 = splat(Wu[0]) * z0 + o0; o0 = splat(Wu[1]) * z1 + o0;
        o0 = splat(Wu[2]) * z2 + o0; o0 = splat(Wu[3]) * z3 + o0;
        o1 = splat(Wu[4]) * z0 + o1; o1 = splat(Wu[5]) * z1 + o1;
        o1 = splat(Wu[6]) * z2 + o1; o1 = splat(Wu[7]) * z3 + o1;

        out[2 * t + k] = make_float4(o0.x, o1.x, o0.y, o1.y);
    }
}

extern "C" void kernel_launch(void* const* d_in, const int* in_sizes, int n_in,
                              void* d_out, int out_size, void* d_ws, size_t ws_size,
                              hipStream_t stream) {
    const float* x  = (const float*)d_in[0];
    const float* w  = (const float*)d_in[1];
    const float* Wm = (const float*)d_in[2];
    const float* bv = (const float*)d_in[3];
    float4* out = (float4*)d_out;

    const int B  = in_sizes[0] / 4;
    const int Bq = B / 4;                       // B divisible by 4 (524288)
    dim3 grid((Bq + 255) / 256), block(256);
    qdqn_kernel<<<grid, block, 0, stream>>>(x, w, Wm, bv, out, Bq);
}